// Round 18
// baseline (71.745 us; speedup 1.0000x reference)
//
#include <hip/hip_runtime.h>

// Point-splat renderer, round 18: dense NB=1024 binsort (measured ~25us) +
// WAVE-COOPERATIVE grouped paint.
//
//  R17 post-mortem: paint 46us, latency-bound (Occ 22%, VALU 4%): per-THREAD
//  serial 15-entry chunk walks + 16MB of histG line waste. Fixes:
//   - histG group-major [(g*NB+b)*4+s]: binsort writes 16B chunks (8MB
//     sectors, cheap); paint stages all 1024 packs coalesced (uint4/thread,
//     16KB LDS): histG fetch 16MB -> 4MB.
//   - wave-cooperative chunks: wave w handles regions b=w,w+16,...; 64 lanes
//     read the contiguous chunk in ONE coalesced round (k=lane; k+=64),
//     sub-tile by count boundaries, LDS atomicMax. 1 issue/chunk instead of
//     15 serial loads/thread -> ~64x more MLP, BW-bound instead of latency.
//
//  Kernel 1 (binsort, 1024x512): project 4 pts/iter (float4x3) -> LDS stash
//  + LDS histogram; exclusive scan (dense); publish group-major packs;
//  replay stash through LDS cursors -> dense (lp<<22|idx) stores.
//  Kernel 2 (paint, 256x1024): block g owns tiles 4g..4g+3 (128x32 strip).
//  winner = max index is order-free -> deterministic.
//
// Inputs: d_in[0] positions (N*3 f32), d_in[1] colors (N*3 f32),
//         d_in[2] camera_pose (16 f32), d_in[3] intrinsics (9 f32),
//         d_in[4] H (1 int), d_in[5] W (1 int)
// Output: (1,3,H,W) f32 flat.

#define NB      1024           // binsort blocks / regions
#define TB      512            // binsort threads per block
#define TBP     1024           // paint threads per block
#define NT      1024           // 32x32 grid of 32x32-px tiles
#define GP      4              // tiles per paint group
#define NG      (NT / GP)      // paint blocks
#define PPB_MAX 4096           // stash capacity (LDS words)
#define IMGW    1024
#define IMGHW   (1024 * 1024)

__host__ __device__ __forceinline__ unsigned align8u(unsigned x) {
    return (x + 7u) & ~7u;
}

__global__ void __launch_bounds__(TB)
binsort_kernel(const float* __restrict__ pos,
               const float* __restrict__ pose,
               const float* __restrict__ intr,
               unsigned* __restrict__ bins,
               unsigned* __restrict__ histG,
               int n, int ppb, int region) {
    __shared__ unsigned stash[PPB_MAX];
    __shared__ unsigned h[NT];
    __shared__ unsigned base_[NT];
    __shared__ unsigned cur[NT];
    __shared__ unsigned sc[TB];

    int tid = threadIdx.x;
    for (int t = tid; t < NT; t += TB) h[t] = 0;
    __syncthreads();

    float r00 = pose[0], r01 = pose[1], r02 = pose[2],  t0 = pose[3];
    float r10 = pose[4], r11 = pose[5], r12 = pose[6],  t1 = pose[7];
    float r20 = pose[8], r21 = pose[9], r22 = pose[10], t2 = pose[11];
    float fx = intr[0], cx = intr[2];
    float fy = intr[4], cy = intr[5];

    int start = blockIdx.x * ppb;            // ppb multiple of 4
    int cnt = min(start + ppb, n) - start;   // multiple of 4 (n mult 4)
    if (cnt < 0) cnt = 0;

    // ---- pass 1: project 4 points/iter (float4 x3), stash + histogram ----
    const float4* p4 = (const float4*)(pos + (size_t)3 * (size_t)start);
    for (int j4 = tid * 4; j4 < cnt; j4 += TB * 4) {
        int g = j4 >> 2;
        float4 A = p4[3 * g + 0];
        float4 B = p4[3 * g + 1];
        float4 C = p4[3 * g + 2];
        float xs0 = A.x, ys0 = A.y, zs0 = A.z;
        float xs1 = A.w, ys1 = B.x, zs1 = B.y;
        float xs2 = B.z, ys2 = B.w, zs2 = C.x;
        float xs3 = C.y, ys3 = C.z, zs3 = C.w;

        unsigned pv[4];
        #define PROJ(K, PX, PY, PZ)                                          \
        {                                                                    \
            float x = r00 * PX + r01 * PY + r02 * PZ + t0;                   \
            float y = r10 * PX + r11 * PY + r12 * PZ + t1;                   \
            float z = r20 * PX + r21 * PY + r22 * PZ + t2;                   \
            float u = fx * x / z + cx;                                       \
            float v = fy * y / z + cy;                                       \
            int xi = (int)u;                                                 \
            int yi = (int)v;                                                 \
            unsigned p = 0xFFFFFFFFu;                                        \
            if (xi >= 0 && xi < IMGW && yi >= 0 && yi < IMGW) {              \
                p = ((unsigned)yi << 10) | (unsigned)xi;                     \
                int tt = ((yi >> 5) << 5) + (xi >> 5);                       \
                atomicAdd(&h[tt], 1u);                                       \
            }                                                                \
            pv[K] = p;                                                       \
        }
        PROJ(0, xs0, ys0, zs0)
        PROJ(1, xs1, ys1, zs1)
        PROJ(2, xs2, ys2, zs2)
        PROJ(3, xs3, ys3, zs3)
        #undef PROJ

        *(uint4*)&stash[j4] = make_uint4(pv[0], pv[1], pv[2], pv[3]);
    }
    __syncthreads();

    // ---- exclusive scan of RAW counts (dense; thread owns tiles 2t,2t+1) --
    unsigned c0 = h[2 * tid];
    unsigned c1 = h[2 * tid + 1];
    unsigned v = c0 + c1;
    sc[tid] = v;
    __syncthreads();
    for (int off = 1; off < TB; off <<= 1) {
        unsigned add = (tid >= off) ? sc[tid - off] : 0u;
        __syncthreads();
        v += add;
        sc[tid] = v;
        __syncthreads();
    }
    base_[2 * tid]     = v - c0 - c1;
    base_[2 * tid + 1] = v - c1;
    __syncthreads();

    // ---- publish GROUP-MAJOR packs histG[(g*NB+b)*4+s]; init cursors ----
    for (int t = tid; t < NT; t += TB) {
        cur[t] = base_[t];
        histG[(size_t)(t >> 2) * (NB * 4) + (blockIdx.x << 2) + (t & 3)] =
            (base_[t] << 16) | h[t];
    }
    __syncthreads();

    // ---- pass 2: replay stash -> dense stores into private region ----
    unsigned* myRegion = bins + (size_t)blockIdx.x * (size_t)region;
    for (int j = tid; j < cnt; j += TB) {
        unsigned pv = stash[j];
        if (pv == 0xFFFFFFFFu) continue;
        unsigned xi = pv & 1023u, yi = pv >> 10;
        unsigned t  = ((yi >> 5) << 5) + (xi >> 5);
        unsigned lp = ((yi & 31u) << 5) + (xi & 31u);
        unsigned slot = atomicAdd(&cur[t], 1u);         // LDS
        myRegion[slot] = (lp << 22) | (unsigned)(start + j);
    }
}

__global__ void __launch_bounds__(TBP)
paint_kernel(const unsigned* __restrict__ bins,
             const unsigned* __restrict__ histG,
             const float* __restrict__ colors,
             float* __restrict__ out,
             int region) {
    __shared__ uint4    hgs[NB];          // 16 KB: staged packs, coalesced
    __shared__ unsigned win[GP * 1024];   // 16 KB: winner idx+1 per px
    int g = blockIdx.x;                   // tile group: tiles 4g..4g+3
    int tid = threadIdx.x;

    hgs[tid] = ((const uint4*)histG)[((size_t)g << 10) + tid];  // TBP==NB
    #pragma unroll
    for (int l = tid; l < GP * 1024; l += TBP) win[l] = 0;
    __syncthreads();

    // wave-cooperative chunk processing: wave w owns regions w, w+16, ...
    int wave = tid >> 6, lane = tid & 63;
    for (int b = wave; b < NB; b += (TBP / 64)) {
        uint4 pk = hgs[b];                // LDS broadcast
        unsigned c0 = pk.x & 0xFFFFu, c1 = pk.y & 0xFFFFu;
        unsigned c2 = pk.z & 0xFFFFu, c3 = pk.w & 0xFFFFu;
        unsigned b01 = c0 + c1, b012 = b01 + c2;
        unsigned total = b012 + c3;
        const unsigned* p = bins + (size_t)b * (size_t)region + (pk.x >> 16);
        for (unsigned k = lane; k < total; k += 64) {   // ONE coalesced round
            unsigned e = p[k];
            unsigned s = (k >= c0) + (k >= b01) + (k >= b012);
            atomicMax(&win[(s << 10) + (e >> 22)], (e & 0x3FFFFFu) + 1u);
        }
    }
    __syncthreads();

    // tiles 4g..4g+3 form a 128x32 px strip at (tx0, ty0)
    int tx0 = ((g * GP) & 31) << 5;
    int ty0 = ((g * GP) >> 5) << 5;
    for (int l = tid; l < GP * 1024; l += TBP) {
        int lx = l & 127, ly = l >> 7;                  // x,y in strip
        int s = lx >> 5, col = lx & 31;
        unsigned w = win[(s << 10) + (ly << 5) + col];
        float r = 0.0f, gc = 0.0f, bl = 0.0f;
        if (w) {
            unsigned wi = w - 1u;
            r  = fminf(fmaxf(colors[3 * wi + 0], 0.0f), 1.0f);
            gc = fminf(fmaxf(colors[3 * wi + 1], 0.0f), 1.0f);
            bl = fminf(fmaxf(colors[3 * wi + 2], 0.0f), 1.0f);
        }
        int p = (ty0 + ly) * IMGW + tx0 + lx;
        out[p] = r;
        out[IMGHW + p] = gc;
        out[2 * IMGHW + p] = bl;
    }
}

// ---------- fallback: memset + single atomic pass + paint ----------

__global__ void proj_simple(const float* __restrict__ pos,
                            const float* __restrict__ pose,
                            const float* __restrict__ intr,
                            const int* __restrict__ Hp,
                            const int* __restrict__ Wp,
                            int* __restrict__ winner, int n) {
    int i = blockIdx.x * blockDim.x + threadIdx.x;
    if (i >= n) return;
    float px = pos[3 * i], py = pos[3 * i + 1], pz = pos[3 * i + 2];
    float x = pose[0] * px + pose[1] * py + pose[2]  * pz + pose[3];
    float y = pose[4] * px + pose[5] * py + pose[6]  * pz + pose[7];
    float z = pose[8] * px + pose[9] * py + pose[10] * pz + pose[11];
    float u = intr[0] * x / z + intr[2];
    float v = intr[4] * y / z + intr[5];
    int xi = (int)u, yi = (int)v;
    int W = *Wp, H = *Hp;
    if (xi >= 0 && xi < W && yi >= 0 && yi < H) atomicMax(&winner[yi * W + xi], i);
}

__global__ void paint_simple(const int* __restrict__ winner,
                             const float* __restrict__ colors,
                             float* __restrict__ out, int HW) {
    int p = blockIdx.x * blockDim.x + threadIdx.x;
    if (p >= HW) return;
    int w = winner[p];
    float r = 0.0f, g = 0.0f, b = 0.0f;
    if (w >= 0) {
        r = fminf(fmaxf(colors[3 * w + 0], 0.0f), 1.0f);
        g = fminf(fmaxf(colors[3 * w + 1], 0.0f), 1.0f);
        b = fminf(fmaxf(colors[3 * w + 2], 0.0f), 1.0f);
    }
    out[p] = r; out[HW + p] = g; out[2 * HW + p] = b;
}

extern "C" void kernel_launch(void* const* d_in, const int* in_sizes, int n_in,
                              void* d_out, int out_size, void* d_ws, size_t ws_size,
                              hipStream_t stream) {
    const float* positions = (const float*)d_in[0];
    const float* colors    = (const float*)d_in[1];
    const float* pose      = (const float*)d_in[2];
    const float* intr      = (const float*)d_in[3];
    const int*   Hp        = (const int*)d_in[4];
    const int*   Wp        = (const int*)d_in[5];
    float* out = (float*)d_out;

    int n  = in_sizes[0] / 3;       // number of points
    int HW = out_size / 3;          // H*W pixels

    int ppb = ((n + NB - 1) / NB + 3) & ~3;             // multiple of 4
    int region = (int)align8u((unsigned)ppb);           // dense regions
    unsigned* bins  = (unsigned*)d_ws;
    unsigned* histG = bins + (size_t)NB * (size_t)region;
    size_t needFast = ((size_t)NB * region + (size_t)NB * NT) * sizeof(unsigned);

    bool fast = (HW == IMGHW) && (n >= 4096) && ((n & 3) == 0) &&
                (ppb <= PPB_MAX) && (n <= 4000000) && (ws_size >= needFast);

    if (fast) {
        binsort_kernel<<<NB, TB, 0, stream>>>(positions, pose, intr,
                                              bins, histG, n, ppb, region);
        paint_kernel<<<NG, TBP, 0, stream>>>(bins, histG, colors, out, region);
        return;
    }

    // ---- fallback ----
    int* winner = (int*)d_ws;
    const int block = 256;
    hipMemsetAsync(winner, 0xFF, (size_t)HW * sizeof(int), stream);
    int grid = (n + block - 1) / block;
    proj_simple<<<grid, block, 0, stream>>>(positions, pose, intr, Hp, Wp,
                                            winner, n);
    int grid2 = (HW + block - 1) / block;
    paint_simple<<<grid2, block, 0, stream>>>(winner, colors, out, HW);
}

// Round 19
// 64.656 us; speedup vs baseline: 1.1096x; 1.1096x over previous
//
#include <hip/hip_runtime.h>

// Point-splat renderer, round 19: dense NB=1024 binsort (unchanged, ~22us) +
// QUARTER-WAVE (16-lane) cooperative grouped paint.
//
//  R18 post-mortem: paint 48us latency-bound: wave-per-region = 64 SERIAL
//  dependent chunk loads per wave (~900cyc each) and only ~15/64 lanes
//  active. Fix: 16-lane groups per region -> 4x concurrent chunk loads per
//  wave AND ~15/16 lane utilization; serial depth 64 -> 16.
//  Chunk phase arithmetic: 16 x 900cyc ~ 6us (+2-round overflow ~8us).
//
//  Kernel 1 (binsort, 1024x512, 4 blk/CU): project 4 pts/iter (float4x3) ->
//  LDS stash + LDS histogram; exclusive scan (dense); publish group-major
//  packs histG[(t>>2)*4096 + (b<<2) + (t&3)]; replay stash through LDS
//  cursors -> dense (lp<<22|idx) stores into private region.
//  Kernel 2 (paint, 256x1024): block g owns tiles 4g..4g+3 (128x32 strip);
//  stage 1024 packs coalesced (uint4/thread); 16-lane group q walks regions
//  b=q,q+64,..., one coalesced 16-lane round per ~15-entry chunk, resolving
//  sub-tile by count boundaries; LDS atomicMax(idx+1); gather colors; CHW.
//  winner = max index is order-free -> deterministic.
//
// Inputs: d_in[0] positions (N*3 f32), d_in[1] colors (N*3 f32),
//         d_in[2] camera_pose (16 f32), d_in[3] intrinsics (9 f32),
//         d_in[4] H (1 int), d_in[5] W (1 int)
// Output: (1,3,H,W) f32 flat.

#define NB      1024           // binsort blocks / regions
#define TB      512            // binsort threads per block
#define TBP     1024           // paint threads per block
#define NT      1024           // 32x32 grid of 32x32-px tiles
#define GP      4              // tiles per paint group
#define NG      (NT / GP)      // paint blocks
#define PPB_MAX 4096           // stash capacity (LDS words)
#define IMGW    1024
#define IMGHW   (1024 * 1024)

__host__ __device__ __forceinline__ unsigned align8u(unsigned x) {
    return (x + 7u) & ~7u;
}

__global__ void __launch_bounds__(TB)
binsort_kernel(const float* __restrict__ pos,
               const float* __restrict__ pose,
               const float* __restrict__ intr,
               unsigned* __restrict__ bins,
               unsigned* __restrict__ histG,
               int n, int ppb, int region) {
    __shared__ unsigned stash[PPB_MAX];
    __shared__ unsigned h[NT];
    __shared__ unsigned base_[NT];
    __shared__ unsigned cur[NT];
    __shared__ unsigned sc[TB];

    int tid = threadIdx.x;
    for (int t = tid; t < NT; t += TB) h[t] = 0;
    __syncthreads();

    float r00 = pose[0], r01 = pose[1], r02 = pose[2],  t0 = pose[3];
    float r10 = pose[4], r11 = pose[5], r12 = pose[6],  t1 = pose[7];
    float r20 = pose[8], r21 = pose[9], r22 = pose[10], t2 = pose[11];
    float fx = intr[0], cx = intr[2];
    float fy = intr[4], cy = intr[5];

    int start = blockIdx.x * ppb;            // ppb multiple of 4
    int cnt = min(start + ppb, n) - start;   // multiple of 4 (n mult 4)
    if (cnt < 0) cnt = 0;

    // ---- pass 1: project 4 points/iter (float4 x3), stash + histogram ----
    const float4* p4 = (const float4*)(pos + (size_t)3 * (size_t)start);
    for (int j4 = tid * 4; j4 < cnt; j4 += TB * 4) {
        int g = j4 >> 2;
        float4 A = p4[3 * g + 0];
        float4 B = p4[3 * g + 1];
        float4 C = p4[3 * g + 2];
        float xs0 = A.x, ys0 = A.y, zs0 = A.z;
        float xs1 = A.w, ys1 = B.x, zs1 = B.y;
        float xs2 = B.z, ys2 = B.w, zs2 = C.x;
        float xs3 = C.y, ys3 = C.z, zs3 = C.w;

        unsigned pv[4];
        #define PROJ(K, PX, PY, PZ)                                          \
        {                                                                    \
            float x = r00 * PX + r01 * PY + r02 * PZ + t0;                   \
            float y = r10 * PX + r11 * PY + r12 * PZ + t1;                   \
            float z = r20 * PX + r21 * PY + r22 * PZ + t2;                   \
            float u = fx * x / z + cx;                                       \
            float v = fy * y / z + cy;                                       \
            int xi = (int)u;                                                 \
            int yi = (int)v;                                                 \
            unsigned p = 0xFFFFFFFFu;                                        \
            if (xi >= 0 && xi < IMGW && yi >= 0 && yi < IMGW) {              \
                p = ((unsigned)yi << 10) | (unsigned)xi;                     \
                int tt = ((yi >> 5) << 5) + (xi >> 5);                       \
                atomicAdd(&h[tt], 1u);                                       \
            }                                                                \
            pv[K] = p;                                                       \
        }
        PROJ(0, xs0, ys0, zs0)
        PROJ(1, xs1, ys1, zs1)
        PROJ(2, xs2, ys2, zs2)
        PROJ(3, xs3, ys3, zs3)
        #undef PROJ

        *(uint4*)&stash[j4] = make_uint4(pv[0], pv[1], pv[2], pv[3]);
    }
    __syncthreads();

    // ---- exclusive scan of RAW counts (dense; thread owns tiles 2t,2t+1) --
    unsigned c0 = h[2 * tid];
    unsigned c1 = h[2 * tid + 1];
    unsigned v = c0 + c1;
    sc[tid] = v;
    __syncthreads();
    for (int off = 1; off < TB; off <<= 1) {
        unsigned add = (tid >= off) ? sc[tid - off] : 0u;
        __syncthreads();
        v += add;
        sc[tid] = v;
        __syncthreads();
    }
    base_[2 * tid]     = v - c0 - c1;
    base_[2 * tid + 1] = v - c1;
    __syncthreads();

    // ---- publish GROUP-MAJOR packs histG[(g*NB+b)*4+s]; init cursors ----
    for (int t = tid; t < NT; t += TB) {
        cur[t] = base_[t];
        histG[(size_t)(t >> 2) * (NB * 4) + (blockIdx.x << 2) + (t & 3)] =
            (base_[t] << 16) | h[t];
    }
    __syncthreads();

    // ---- pass 2: replay stash -> dense stores into private region ----
    unsigned* myRegion = bins + (size_t)blockIdx.x * (size_t)region;
    for (int j = tid; j < cnt; j += TB) {
        unsigned pv = stash[j];
        if (pv == 0xFFFFFFFFu) continue;
        unsigned xi = pv & 1023u, yi = pv >> 10;
        unsigned t  = ((yi >> 5) << 5) + (xi >> 5);
        unsigned lp = ((yi & 31u) << 5) + (xi & 31u);
        unsigned slot = atomicAdd(&cur[t], 1u);         // LDS
        myRegion[slot] = (lp << 22) | (unsigned)(start + j);
    }
}

__global__ void __launch_bounds__(TBP)
paint_kernel(const unsigned* __restrict__ bins,
             const unsigned* __restrict__ histG,
             const float* __restrict__ colors,
             float* __restrict__ out,
             int region) {
    __shared__ uint4    hgs[NB];          // 16 KB: staged packs, coalesced
    __shared__ unsigned win[GP * 1024];   // 16 KB: winner idx+1 per px
    int g = blockIdx.x;                   // tile group: tiles 4g..4g+3
    int tid = threadIdx.x;

    hgs[tid] = ((const uint4*)histG)[((size_t)g << 10) + tid];  // TBP==NB
    #pragma unroll
    for (int l = tid; l < GP * 1024; l += TBP) win[l] = 0;
    __syncthreads();

    // 16-lane-group cooperative chunks: group q owns regions q, q+64, ...
    int grp = tid >> 4, lane16 = tid & 15;
    for (int b = grp; b < NB; b += (TBP / 16)) {        // 16 serial iters
        uint4 pk = hgs[b];                // LDS
        unsigned c0 = pk.x & 0xFFFFu, c1 = pk.y & 0xFFFFu;
        unsigned c2 = pk.z & 0xFFFFu, c3 = pk.w & 0xFFFFu;
        unsigned b01 = c0 + c1, b012 = b01 + c2;
        unsigned total = b012 + c3;
        const unsigned* p = bins + (size_t)b * (size_t)region + (pk.x >> 16);
        for (unsigned k = lane16; k < total; k += 16) { // ~1 coalesced round
            unsigned e = p[k];
            unsigned s = (k >= c0) + (k >= b01) + (k >= b012);
            atomicMax(&win[(s << 10) + (e >> 22)], (e & 0x3FFFFFu) + 1u);
        }
    }
    __syncthreads();

    // tiles 4g..4g+3 form a 128x32 px strip at (tx0, ty0)
    int tx0 = ((g * GP) & 31) << 5;
    int ty0 = ((g * GP) >> 5) << 5;
    for (int l = tid; l < GP * 1024; l += TBP) {
        int lx = l & 127, ly = l >> 7;                  // x,y in strip
        int s = lx >> 5, col = lx & 31;
        unsigned w = win[(s << 10) + (ly << 5) + col];
        float r = 0.0f, gc = 0.0f, bl = 0.0f;
        if (w) {
            unsigned wi = w - 1u;
            r  = fminf(fmaxf(colors[3 * wi + 0], 0.0f), 1.0f);
            gc = fminf(fmaxf(colors[3 * wi + 1], 0.0f), 1.0f);
            bl = fminf(fmaxf(colors[3 * wi + 2], 0.0f), 1.0f);
        }
        int p = (ty0 + ly) * IMGW + tx0 + lx;
        out[p] = r;
        out[IMGHW + p] = gc;
        out[2 * IMGHW + p] = bl;
    }
}

// ---------- fallback: memset + single atomic pass + paint ----------

__global__ void proj_simple(const float* __restrict__ pos,
                            const float* __restrict__ pose,
                            const float* __restrict__ intr,
                            const int* __restrict__ Hp,
                            const int* __restrict__ Wp,
                            int* __restrict__ winner, int n) {
    int i = blockIdx.x * blockDim.x + threadIdx.x;
    if (i >= n) return;
    float px = pos[3 * i], py = pos[3 * i + 1], pz = pos[3 * i + 2];
    float x = pose[0] * px + pose[1] * py + pose[2]  * pz + pose[3];
    float y = pose[4] * px + pose[5] * py + pose[6]  * pz + pose[7];
    float z = pose[8] * px + pose[9] * py + pose[10] * pz + pose[11];
    float u = intr[0] * x / z + intr[2];
    float v = intr[4] * y / z + intr[5];
    int xi = (int)u, yi = (int)v;
    int W = *Wp, H = *Hp;
    if (xi >= 0 && xi < W && yi >= 0 && yi < H) atomicMax(&winner[yi * W + xi], i);
}

__global__ void paint_simple(const int* __restrict__ winner,
                             const float* __restrict__ colors,
                             float* __restrict__ out, int HW) {
    int p = blockIdx.x * blockDim.x + threadIdx.x;
    if (p >= HW) return;
    int w = winner[p];
    float r = 0.0f, g = 0.0f, b = 0.0f;
    if (w >= 0) {
        r = fminf(fmaxf(colors[3 * w + 0], 0.0f), 1.0f);
        g = fminf(fmaxf(colors[3 * w + 1], 0.0f), 1.0f);
        b = fminf(fmaxf(colors[3 * w + 2], 0.0f), 1.0f);
    }
    out[p] = r; out[HW + p] = g; out[2 * HW + p] = b;
}

extern "C" void kernel_launch(void* const* d_in, const int* in_sizes, int n_in,
                              void* d_out, int out_size, void* d_ws, size_t ws_size,
                              hipStream_t stream) {
    const float* positions = (const float*)d_in[0];
    const float* colors    = (const float*)d_in[1];
    const float* pose      = (const float*)d_in[2];
    const float* intr      = (const float*)d_in[3];
    const int*   Hp        = (const int*)d_in[4];
    const int*   Wp        = (const int*)d_in[5];
    float* out = (float*)d_out;

    int n  = in_sizes[0] / 3;       // number of points
    int HW = out_size / 3;          // H*W pixels

    int ppb = ((n + NB - 1) / NB + 3) & ~3;             // multiple of 4
    int region = (int)align8u((unsigned)ppb);           // dense regions
    unsigned* bins  = (unsigned*)d_ws;
    unsigned* histG = bins + (size_t)NB * (size_t)region;
    size_t needFast = ((size_t)NB * region + (size_t)NB * NT) * sizeof(unsigned);

    bool fast = (HW == IMGHW) && (n >= 4096) && ((n & 3) == 0) &&
                (ppb <= PPB_MAX) && (n <= 4000000) && (ws_size >= needFast);

    if (fast) {
        binsort_kernel<<<NB, TB, 0, stream>>>(positions, pose, intr,
                                              bins, histG, n, ppb, region);
        paint_kernel<<<NG, TBP, 0, stream>>>(bins, histG, colors, out, region);
        return;
    }

    // ---- fallback ----
    int* winner = (int*)d_ws;
    const int block = 256;
    hipMemsetAsync(winner, 0xFF, (size_t)HW * sizeof(int), stream);
    int grid = (n + block - 1) / block;
    proj_simple<<<grid, block, 0, stream>>>(positions, pose, intr, Hp, Wp,
                                            winner, n);
    int grid2 = (HW + block - 1) / block;
    paint_simple<<<grid2, block, 0, stream>>>(winner, colors, out, HW);
}